// Round 10
// baseline (367.973 us; speedup 1.0000x reference)
//
#include <hip/hip_runtime.h>
#include <hip/hip_bf16.h>

// Bidirectional GRU (Keras reset_after=True) + dense classifier.
// B=32, T=160, D=512, H=256, C=6625.
// Round 10: scan v7 -- gate-aligned wave ownership. 8 waves x 512 thr; wave w
//   owns z,r,h for cols [32w,32w+32) (6 n-tiles x 8 kk = 48 MFMA). Gate dots
//   land in the wave's own acc regs (row0 = lanes 0-15, reg 0; layout proven
//   in v6) -> no sums LDS, no 2nd barrier, h_old in lane regs. 1 barrier/step.
//   v6 audit: 2775 cyc/step = 1863 MFMA floor + ~900 structure overhead.
//   proj_mfma / cls_mfma2 / packs unchanged from R9.

#define B 32
#define T 160
#define D 512
#define H 256
#define C 6625
#define H3 768
#define NT16 416                  // 26*16 16-col W tiles (padded past 6625)
#define KP_PER_DIR 393216         // proj kernel pack: 48 nt * 64 kc * 16 * 8
#define RKB_PER_DIR 196608        // scan rk pack: 48 nt * 32 kc * 16 * 8

typedef __attribute__((ext_vector_type(8))) short short8v;
typedef __attribute__((ext_vector_type(4))) float float4v;

__device__ inline unsigned short f2bf(float v) {
    __hip_bfloat16 b = __float2bfloat16(v);
    return *reinterpret_cast<unsigned short*>(&b);
}
__device__ inline float bf2f(unsigned short u) {
    return __uint_as_float((unsigned int)u << 16);
}

// ---------------------------------------------------------------- pack rkB (scan B-fragments)
// rkB[dir][nt48][kc32][col16][i8] = bf16( rk[kc*8+i][nt*16+col] )
__global__ __launch_bounds__(256) void pack_rkB_kernel(
    const float* __restrict__ rkf, const float* __restrict__ rkb,
    unsigned short* __restrict__ rkB)
{
    const int idx = blockIdx.x * 256 + threadIdx.x;   // < 196608
    const int dir = blockIdx.y;
    const float* rk = dir ? rkb : rkf;
    const int i   = idx & 7;
    const int col = (idx >> 3) & 15;
    const int kc  = (idx >> 7) & 31;
    const int nt  = idx >> 12;         // 0..47
    rkB[dir * RKB_PER_DIR + idx] = f2bf(rk[(kc * 8 + i) * H3 + nt * 16 + col]);
}

// ---------------------------------------------------------------- pack W
// Wp[nt][kc][col][i] = bf16( W[kc*8+i][nt*16+col] ), zero-padded cols.
__global__ __launch_bounds__(256) void pack_W_kernel(
    const float* __restrict__ W, unsigned short* __restrict__ Wp)
{
    const int idx = blockIdx.x * 256 + threadIdx.x;   // < 416*8192
    const int i   = idx & 7;
    const int col = (idx >> 3) & 15;
    const int kc  = (idx >> 7) & 63;
    const int nt  = idx >> 13;
    const int k = kc * 8 + i;
    const int c = nt * 16 + col;
    const float v = (c < C) ? W[k * C + c] : 0.f;
    Wp[idx] = f2bf(v);
}

// ---------------------------------------------------------------- pack xb
// xb[t*32+b][k] = bf16( x[b][t][k] ) -- time-major, coalesced in k.
__global__ __launch_bounds__(256) void pack_xb_kernel(
    const float* __restrict__ x, unsigned short* __restrict__ xb)
{
    const int idx = blockIdx.x * 256 + threadIdx.x;   // < 2,621,440
    const int k   = idx & 511;
    const int row = idx >> 9;          // t*32+b
    const int t   = row >> 5;
    const int b   = row & 31;
    xb[idx] = f2bf(x[(b * T + t) * 512 + k]);
}

// ---------------------------------------------------------------- pack kern
// kernP[dir][nt48][kc64][col16][i8] = bf16( kern[kc*8+i][nt*16+col] )
__global__ __launch_bounds__(256) void pack_kern_kernel(
    const float* __restrict__ kf, const float* __restrict__ kb,
    unsigned short* __restrict__ kernP)
{
    const int idx = blockIdx.x * 256 + threadIdx.x;   // < 393216
    const int dir = blockIdx.y;
    const float* kern = dir ? kb : kf;
    const int i   = idx & 7;
    const int col = (idx >> 3) & 15;
    const int kc  = (idx >> 7) & 63;
    const int nt  = idx >> 13;         // 0..47
    kernP[dir * KP_PER_DIR + idx] = f2bf(kern[(kc * 8 + i) * H3 + nt * 16 + col]);
}

// ---------------------------------------------------------------- K1: proj (MFMA)
// grid (240, 2). Output xpb in BF16 (scan reads it; halves scan HBM bytes).
__global__ __launch_bounds__(256) void proj_mfma_kernel(
    const unsigned short* __restrict__ xb,     // [5120][512] bf16
    const unsigned short* __restrict__ kernP,  // [2][48][64][16][8]
    const float* __restrict__ bias_f,          // [2][H3]
    const float* __restrict__ bias_b,
    unsigned short* __restrict__ xpb)          // [2*5120][768] bf16
{
    const int bid = blockIdx.x;
    const int ct  = bid / 40;          // 0..5
    const int rt  = bid % 40;          // 0..39
    const int dir = blockIdx.y;
    const int lane = threadIdx.x & 63;
    const int wid  = threadIdx.x >> 6;
    const int wm = wid >> 1, wn = wid & 1;
    const int rowBase = rt * 128 + wm * 64;
    const int lrow = lane & 15;
    const int lk8  = lane >> 4;        // 0..3
    const float* bias = dir ? bias_b : bias_f;

    float4v acc[4][4];
#pragma unroll
    for (int i = 0; i < 4; ++i)
#pragma unroll
        for (int k = 0; k < 4; ++k) acc[i][k] = (float4v){0.f, 0.f, 0.f, 0.f};

    const short* A  = (const short*)xb;
    const short* Bp = (const short*)(kernP + dir * KP_PER_DIR);
    const int ntBase = ct * 8 + wn * 4;

    int arow[4];
#pragma unroll
    for (int mt = 0; mt < 4; ++mt) {
        const int r0 = rowBase + mt * 16;
        const int s  = r0 >> 5;
        arow[mt] = (dir ? (159 - s) : s) * 32 + (r0 & 31);
    }

    for (int k0 = 0; k0 < 512; k0 += 32) {
        short8v aF[4], bF[4];
#pragma unroll
        for (int mt = 0; mt < 4; ++mt)
            aF[mt] = *(const short8v*)&A[(arow[mt] + lrow) * 512 + k0 + lk8 * 8];
#pragma unroll
        for (int ntw = 0; ntw < 4; ++ntw)
            bF[ntw] = *(const short8v*)&Bp[((ntBase + ntw) * 64 + (k0 >> 3) + lk8) * 128 + lrow * 8];
#pragma unroll
        for (int mt = 0; mt < 4; ++mt)
#pragma unroll
            for (int ntw = 0; ntw < 4; ++ntw)
                acc[mt][ntw] = __builtin_amdgcn_mfma_f32_16x16x32_bf16(
                    aF[mt], bF[ntw], acc[mt][ntw], 0, 0, 0);
    }

    const int orow = (lane >> 4) * 4;   // C/D: col=lane&15, row=(lane>>4)*4+reg
#pragma unroll
    for (int ntw = 0; ntw < 4; ++ntw) {
        const int c = (ntBase + ntw) * 16 + lrow;   // 0..767
        const float bc = bias[c];
#pragma unroll
        for (int mt = 0; mt < 4; ++mt)
#pragma unroll
            for (int v = 0; v < 4; ++v)
                xpb[(size_t)(dir * 5120 + rowBase + mt * 16 + orow + v) * H3 + c]
                    = f2bf(acc[mt][ntw][v] + bc);
    }
}

// ---------------------------------------------------------------- K2: scan v7 (MFMA, gate-aligned waves)
// grid 64 = (dir<<5)|b, block 512 = 8 waves. Wave w owns cols [32w, 32w+32)
// for ALL 3 gates: 6 n-tiles (z:2w,2w+1 | r:16+2w,.. | h:32+2w,..) x 8 kk
// = 48 MFMA/step. Gate dots land in the wave's own accs (row0 = lanes 0-15,
// reg 0). h_old in lane regs. ONE barrier per step.
__global__ __launch_bounds__(512, 2) void gru_scan_v7(
    const unsigned short* __restrict__ xpb, // [2][T][B][H3] bf16
    const unsigned short* __restrict__ rkB, // [2][48][32][16][8]
    const float* __restrict__ bias_f,
    const float* __restrict__ bias_b,
    __hip_bfloat16* __restrict__ hcatb)    // [T][B][2H] bf16
{
    const int bid = blockIdx.x;
    const int dir = bid >> 5;
    const int b   = bid & 31;
    const int tid = threadIdx.x;
    const int wv  = tid >> 6;          // 0..7
    const int lane = tid & 63;
    const int lrow = lane & 15;
    const int lk8  = lane >> 4;        // 0..3
    const float* bias = dir ? bias_b : bias_f;
    const short* Bp = (const short*)(rkB + (size_t)dir * RKB_PER_DIR);

    // ---- one-time: B fragments (6 n-tiles x 8 kk); AGPR-native for MFMA ----
    short8v bw[6][8];
#pragma unroll
    for (int g = 0; g < 3; ++g)
#pragma unroll
        for (int i = 0; i < 2; ++i)
#pragma unroll
            for (int kk = 0; kk < 8; ++kk)
                bw[g * 2 + i][kk] = *(const short8v*)
                    &Bp[((g * 16 + 2 * wv + i) * 32 + kk * 4 + lk8) * 128 + lrow * 8];

    // lane l<16 owns cols c0 = 32w+l and c1 = c0+16
    const int c0 = wv * 32 + lrow;
    const int c1 = c0 + 16;
    float rb[3][2];
#pragma unroll
    for (int g = 0; g < 3; ++g) {
        rb[g][0] = bias[H3 + g * 256 + c0];
        rb[g][1] = bias[H3 + g * 256 + c1];
    }
    float h0 = 0.f, h1 = 0.f;          // h_old in regs (lane-owned cols)

    __shared__ __align__(16) unsigned short hus[256];  // bf16 h (A operand)
    if (tid < 256) hus[tid] = 0;
    __syncthreads();

    for (int s = 0; s < T; ++s) {
        // prefetch x-projection for own cols (hides under MFMA)
        const unsigned short* xrow = xpb + ((size_t)(dir * T + s) * B + b) * H3;
        float xg[3][2];
        if (lane < 16) {
#pragma unroll
            for (int g = 0; g < 3; ++g) {
                xg[g][0] = bf2f(xrow[g * 256 + c0]);
                xg[g][1] = bf2f(xrow[g * 256 + c1]);
            }
        }

        float4v acc[6];
#pragma unroll
        for (int i = 0; i < 6; ++i) acc[i] = (float4v){0.f, 0.f, 0.f, 0.f};
#pragma unroll
        for (int kk = 0; kk < 8; ++kk) {
            short8v aF = *(const short8v*)&hus[kk * 32 + lk8 * 8];  // broadcast
#pragma unroll
            for (int i = 0; i < 6; ++i)
                acc[i] = __builtin_amdgcn_mfma_f32_16x16x32_bf16(aF, bw[i][kk], acc[i], 0, 0, 0);
        }

        if (lane < 16) {               // row 0 = lanes 0-15, reg 0 (v6-proven)
            const float z0 = 1.f / (1.f + __expf(-(xg[0][0] + acc[0][0] + rb[0][0])));
            const float z1 = 1.f / (1.f + __expf(-(xg[0][1] + acc[1][0] + rb[0][1])));
            const float r0 = 1.f / (1.f + __expf(-(xg[1][0] + acc[2][0] + rb[1][0])));
            const float r1 = 1.f / (1.f + __expf(-(xg[1][1] + acc[3][0] + rb[1][1])));
            const float p0 = xg[2][0] + r0 * (acc[4][0] + rb[2][0]);
            const float p1 = xg[2][1] + r1 * (acc[5][0] + rb[2][1]);
            const float e0 = __expf(2.f * p0);
            const float e1 = __expf(2.f * p1);
            const float t0 = 1.f - 2.f / (e0 + 1.f);    // tanh, inf-safe
            const float t1 = 1.f - 2.f / (e1 + 1.f);
            h0 = z0 * h0 + (1.f - z0) * t0;
            h1 = z1 * h1 + (1.f - z1) * t1;
            hus[c0] = f2bf(h0);
            hus[c1] = f2bf(h1);
            const int ta = dir ? (T - 1 - s) : s;
            __hip_bfloat16* hrow = hcatb + (size_t)(ta * B + b) * 512 + dir * 256;
            hrow[c0] = __float2bfloat16(h0);
            hrow[c1] = __float2bfloat16(h1);
        }
        __syncthreads();               // h_{s+1} visible for next A-broadcast
    }
}

// ---------------------------------------------------------------- K3: cls v2 (MFMA, LDS A)
// grid 1040 = 26 ctn x 40 rt, ct-major (256-col W slice = 256 KB L2-resident).
// Block 128 rows x 256 cols, 4 waves 2x2 -> wave 64x128 (mt=4, nt=8).
// A staged once in 128 KB LDS, XOR-swizzled: byte ^= (row&7)<<4.
__global__ __launch_bounds__(256) void cls_mfma2_kernel(
    const unsigned short* __restrict__ hcatb,  // [5120][512] bf16
    const unsigned short* __restrict__ Wp,     // [416][64][16][8]
    const float* __restrict__ bias,
    float* __restrict__ out)
{
    const int bid = blockIdx.x;
    const int ctn = bid / 40;          // 0..25
    const int rt  = bid % 40;          // 0..39
    const int tid = threadIdx.x;
    const int lane = tid & 63;
    const int wid  = tid >> 6;
    const int wm = wid >> 1, wn = wid & 1;
    const int lrow = lane & 15;
    const int lk8  = lane >> 4;        // 0..3
    const int r0   = rt * 128;

    __shared__ __align__(16) unsigned short As[128 * 512];   // 128 KB swizzled

    {   // stage 128x512 bf16: 32 x 16B chunks per thread, coalesced global
        const uint4* src = (const uint4*)hcatb;    // row = 64 uint4
        for (int it = 0; it < 32; ++it) {
            const int v   = it * 256 + tid;        // 0..8191
            const int row = v >> 6;
            const int c16 = (v & 63) << 4;         // byte offset in row
            const uint4 d = src[(size_t)(r0 + row) * 64 + (v & 63)];
            *(uint4*)((char*)As + row * 1024 + (c16 ^ ((row & 7) << 4))) = d;
        }
    }
    __syncthreads();

    float4v acc[4][8];
#pragma unroll
    for (int i = 0; i < 4; ++i)
#pragma unroll
        for (int k = 0; k < 8; ++k) acc[i][k] = (float4v){0.f, 0.f, 0.f, 0.f};

    const short* Bp = (const short*)Wp;
    const int ntBase = ctn * 16 + wn * 8;

    for (int k0 = 0; k0 < 512; k0 += 32) {
        short8v aF[4], bF[8];
#pragma unroll
        for (int mt = 0; mt < 4; ++mt) {
            const int row = wm * 64 + mt * 16 + lrow;
            const int cb  = (k0 * 2 + lk8 * 16) ^ ((row & 7) << 4);
            aF[mt] = *(const short8v*)((const char*)As + row * 1024 + cb);
        }
#pragma unroll
        for (int ntw = 0; ntw < 8; ++ntw)
            bF[ntw] = *(const short8v*)&Bp[((ntBase + ntw) * 64 + (k0 >> 3) + lk8) * 128 + lrow * 8];
#pragma unroll
        for (int mt = 0; mt < 4; ++mt)
#pragma unroll
            for (int ntw = 0; ntw < 8; ++ntw)
                acc[mt][ntw] = __builtin_amdgcn_mfma_f32_16x16x32_bf16(
                    aF[mt], bF[ntw], acc[mt][ntw], 0, 0, 0);
    }

    const int orow = (lane >> 4) * 4;   // C/D: col=lane&15, row=(lane>>4)*4+reg
#pragma unroll
    for (int ntw = 0; ntw < 8; ++ntw) {
        const int c = (ntBase + ntw) * 16 + lrow;
        if (c >= C) continue;
        const float bc = bias[c];
#pragma unroll
        for (int mt = 0; mt < 4; ++mt)
#pragma unroll
            for (int v = 0; v < 4; ++v)
                out[(size_t)(r0 + wm * 64 + mt * 16 + orow + v) * C + c]
                    = acc[mt][ntw][v] + bc;
    }
}

// ============================ fallback fp32 path (small ws) ============================
__global__ __launch_bounds__(256) void proj_kernel(
    const float* __restrict__ x, const float* __restrict__ kf,
    const float* __restrict__ kb, const float* __restrict__ bias_f,
    const float* __restrict__ bias_b, float* __restrict__ xp)
{
    const int ct  = blockIdx.x;
    const int s   = blockIdx.y;
    const int dir = blockIdx.z;
    const int tid = threadIdx.x;
    const int t   = dir ? (T - 1 - s) : s;
    const float* kern = dir ? kb : kf;
    const float* bias = dir ? bias_b : bias_f;

    __shared__ float xs[32 * 512];
    for (int it = 0; it < 16; ++it) {
        int v = it * 256 + tid, row = v >> 7, k4 = v & 127;
        *(float4*)&xs[(row << 9) + (k4 << 2)] =
            *(const float4*)&x[((row * T + t) << 9) + (k4 << 2)];
    }
    __syncthreads();

    const int col = ct * 256 + tid;
    float acc[32];
#pragma unroll
    for (int r = 0; r < 32; ++r) acc[r] = 0.f;
    for (int k = 0; k < 512; k += 4) {
        float w0 = kern[(k + 0) * H3 + col];
        float w1 = kern[(k + 1) * H3 + col];
        float w2 = kern[(k + 2) * H3 + col];
        float w3 = kern[(k + 3) * H3 + col];
#pragma unroll
        for (int r = 0; r < 32; ++r) {
            float4 xv = *(const float4*)&xs[(r << 9) + k];
            acc[r] += xv.x * w0 + xv.y * w1 + xv.z * w2 + xv.w * w3;
        }
    }
    const float bb = bias[col];
    for (int r = 0; r < 32; ++r)
        xp[((dir * T + s) * B + r) * H3 + col] = acc[r] + bb;
}

__global__ __launch_bounds__(1024) void gru_scan_f32(
    const float* __restrict__ xp,
    const float* __restrict__ rk_f, const float* __restrict__ rk_b,
    const float* __restrict__ bias_f, const float* __restrict__ bias_b,
    float* __restrict__ hcat)
{
    const int bid = blockIdx.x;
    const int dir = bid >> 5;
    const int b   = bid & 31;
    const int tid = threadIdx.x;
    const int kg  = tid >> 8;
    const int j   = tid & 255;
    const int k0  = kg << 6;
    const float* rk   = dir ? rk_b : rk_f;
    const float* bias = dir ? bias_b : bias_f;
    const float rbz = bias[H3 + j];
    const float rbr = bias[H3 + 256 + j];
    const float rbh = bias[H3 + 512 + j];

    __shared__ float h[256];
    __shared__ float part[3][4][256];
    if (tid < 256) h[tid] = 0.f;
    __syncthreads();

    for (int s = 0; s < T; ++s) {
        const float* xrow = xp + ((dir * T + s) * B + b) * H3;
        float az = 0.f, ar = 0.f, ah = 0.f;
#pragma unroll 4
        for (int k = k0; k < k0 + 64; k += 4) {
            float4 h4 = *(const float4*)&h[k];
            const float* rkp = rk + k * H3 + j;
            az += h4.x * rkp[0];       ar += h4.x * rkp[256];       ah += h4.x * rkp[512];
            az += h4.y * rkp[H3];      ar += h4.y * rkp[H3+256];    ah += h4.y * rkp[H3+512];
            az += h4.z * rkp[2*H3];    ar += h4.z * rkp[2*H3+256];  ah += h4.z * rkp[2*H3+512];
            az += h4.w * rkp[3*H3];    ar += h4.w * rkp[3*H3+256];  ah += h4.w * rkp[3*H3+512];
        }
        part[0][kg][j] = az; part[1][kg][j] = ar; part[2][kg][j] = ah;
        __syncthreads();
        if (tid < 256) {
            const float sz = part[0][0][tid]+part[0][1][tid]+part[0][2][tid]+part[0][3][tid];
            const float sr = part[1][0][tid]+part[1][1][tid]+part[1][2][tid]+part[1][3][tid];
            const float sh = part[2][0][tid]+part[2][1][tid]+part[2][2][tid]+part[2][3][tid];
            const float xz = xrow[tid], xr = xrow[256+tid], xh = xrow[512+tid];
            const float z  = 1.f / (1.f + __expf(-(xz + sz + rbz)));
            const float r  = 1.f / (1.f + __expf(-(xr + sr + rbr)));
            const float pre = xh + r * (sh + rbh);
            const float e2  = __expf(2.f * pre);
            const float hh  = 1.f - 2.f / (e2 + 1.f);
            const float hn  = z * h[tid] + (1.f - z) * hh;
            h[tid] = hn;
            const int ta = dir ? (T - 1 - s) : s;
            hcat[(ta * B + b) * (2 * H) + dir * H + tid] = hn;
        }
        __syncthreads();
    }
}

__global__ __launch_bounds__(256) void cls_f32_kernel(
    const float* __restrict__ hcat, const float* __restrict__ W,
    const float* __restrict__ bias, float* __restrict__ out)
{
    const int bid = blockIdx.x;
    const int ct  = bid / 160;
    const int rt  = bid % 160;
    const int tid = threadIdx.x;
    const int r0  = rt * 32;

    __shared__ float hs[32 * 512];
    for (int it = 0; it < 16; ++it) {
        int v = it * 256 + tid, row = v >> 7, k4 = v & 127;
        *(float4*)&hs[(row << 9) + (k4 << 2)] =
            *(const float4*)&hcat[((r0 + row) << 9) + (k4 << 2)];
    }
    __syncthreads();

    const int c0 = ct * 512 + tid;
    const int c1 = c0 + 256;
    const bool v1 = (c1 < C);
    float acc0[32], acc1[32];
#pragma unroll
    for (int r = 0; r < 32; ++r) { acc0[r] = 0.f; acc1[r] = 0.f; }
    for (int k = 0; k < 512; k += 4) {
        const float* wp = W + k * C;
        float w00 = wp[c0], w01 = wp[C+c0], w02 = wp[2*C+c0], w03 = wp[3*C+c0];
        float w10 = v1 ? wp[c1] : 0.f, w11 = v1 ? wp[C+c1] : 0.f;
        float w12 = v1 ? wp[2*C+c1] : 0.f, w13 = v1 ? wp[3*C+c1] : 0.f;
#pragma unroll
        for (int r = 0; r < 32; ++r) {
            float4 hv = *(const float4*)&hs[(r << 9) + k];
            acc0[r] += hv.x*w00 + hv.y*w01 + hv.z*w02 + hv.w*w03;
            acc1[r] += hv.x*w10 + hv.y*w11 + hv.z*w12 + hv.w*w13;
        }
    }
    const float b0 = bias[c0];
    const float b1 = v1 ? bias[c1] : 0.f;
    for (int r = 0; r < 32; ++r) {
        out[(size_t)(r0+r)*C + c0] = acc0[r] + b0;
        if (v1) out[(size_t)(r0+r)*C + c1] = acc1[r] + b1;
    }
}

// ---------------------------------------------------------------- launch
extern "C" void kernel_launch(void* const* d_in, const int* in_sizes, int n_in,
                              void* d_out, int out_size, void* d_ws, size_t ws_size,
                              hipStream_t stream) {
    const float* x     = (const float*)d_in[0];
    const float* kf    = (const float*)d_in[1];
    const float* rkf   = (const float*)d_in[2];
    const float* biasf = (const float*)d_in[3];
    const float* kb    = (const float*)d_in[4];
    const float* rkb   = (const float*)d_in[5];
    const float* biasb = (const float*)d_in[6];
    const float* W     = (const float*)d_in[7];
    const float* bvec  = (const float*)d_in[8];
    float* out = (float*)d_out;

    const size_t rkB_bytes   = (size_t)2 * RKB_PER_DIR * 2;       //   786,432
    const size_t Wp_bytes    = (size_t)NT16 * 8192 * 2;           // 6,815,744
    const size_t hcatb_bytes = (size_t)T * B * 2 * H * 2;         // 5,242,880
    const size_t planA_bytes = rkB_bytes + Wp_bytes + hcatb_bytes;

    // d_out (135.7 MB) carved up; all regions dead before cls writes out:
    //   [0, 15.7 MB)        xpb   [2*5120][768] bf16
    //   [31.5, 36.7 MB)     xb    [5120][512] bf16
    //   [36.7, 38.3 MB)     kernP [2][393216] bf16
    unsigned short* xpb   = (unsigned short*)out;
    unsigned short* xb    = (unsigned short*)((char*)out + (size_t)2 * 5120 * H3 * 4);
    unsigned short* kernP = (unsigned short*)((char*)xb + (size_t)5120 * 512 * 2);

    if (ws_size >= planA_bytes) {
        char* wsb = (char*)d_ws;
        unsigned short* rkB   = (unsigned short*)wsb;
        unsigned short* Wp    = (unsigned short*)(wsb + rkB_bytes);
        __hip_bfloat16* hcatb = (__hip_bfloat16*)(wsb + rkB_bytes + Wp_bytes);

        pack_rkB_kernel<<<dim3(768, 2), 256, 0, stream>>>(rkf, rkb, rkB);
        pack_W_kernel<<<13312, 256, 0, stream>>>(W, Wp);
        pack_xb_kernel<<<10240, 256, 0, stream>>>(x, xb);
        pack_kern_kernel<<<dim3(1536, 2), 256, 0, stream>>>(kf, kb, kernP);

        proj_mfma_kernel<<<dim3(240, 2), 256, 0, stream>>>(xb, kernP, biasf, biasb, xpb);

        gru_scan_v7<<<64, 512, 0, stream>>>(xpb, rkB, biasf, biasb, hcatb);

        cls_mfma2_kernel<<<1040, 256, 0, stream>>>((const unsigned short*)hcatb,
                                                   Wp, bvec, out);
    } else {
        // fp32 fallback (round-2 path)
        float* xp   = out;
        float* hcat = (float*)d_ws;     // 10.5 MB
        dim3 g1(3, T, 2);
        proj_kernel<<<g1, 256, 0, stream>>>(x, kf, kb, biasf, biasb, xp);
        gru_scan_f32<<<64, 1024, 0, stream>>>(xp, rkf, rkb, biasf, biasb, hcat);
        cls_f32_kernel<<<13 * 160, 256, 0, stream>>>(hcat, W, bvec, out);
    }
}

// Round 11
// 299.022 us; speedup vs baseline: 1.2306x; 1.2306x over previous
//
#include <hip/hip_runtime.h>
#include <hip/hip_bf16.h>

// Bidirectional GRU (Keras reset_after=True) + dense classifier.
// B=32, T=160, D=512, H=256, C=6625.
// Round 11: revert scan to v6 (R9's proven 185 us; v7's 6-nt/wave spilled
//   ~64 weight frags -> L2 re-stream, 233 us). cls -> 64-row tiles (64 KB
//   LDS, 2 blocks/CU vs 1) to unhide staging latency; wave tile 32x128.
//   proj_mfma / packs unchanged from R9.

#define B 32
#define T 160
#define D 512
#define H 256
#define C 6625
#define H3 768
#define NT16 416                  // 26*16 16-col W tiles (padded past 6625)
#define KP_PER_DIR 393216         // proj kernel pack: 48 nt * 64 kc * 16 * 8
#define RKB_PER_DIR 196608        // scan rk pack: 48 nt * 32 kc * 16 * 8

typedef __attribute__((ext_vector_type(8))) short short8v;
typedef __attribute__((ext_vector_type(4))) float float4v;

__device__ inline unsigned short f2bf(float v) {
    __hip_bfloat16 b = __float2bfloat16(v);
    return *reinterpret_cast<unsigned short*>(&b);
}
__device__ inline float bf2f(unsigned short u) {
    return __uint_as_float((unsigned int)u << 16);
}

// ---------------------------------------------------------------- pack rkB (scan B-fragments)
// rkB[dir][nt48][kc32][col16][i8] = bf16( rk[kc*8+i][nt*16+col] )
__global__ __launch_bounds__(256) void pack_rkB_kernel(
    const float* __restrict__ rkf, const float* __restrict__ rkb,
    unsigned short* __restrict__ rkB)
{
    const int idx = blockIdx.x * 256 + threadIdx.x;   // < 196608
    const int dir = blockIdx.y;
    const float* rk = dir ? rkb : rkf;
    const int i   = idx & 7;
    const int col = (idx >> 3) & 15;
    const int kc  = (idx >> 7) & 31;
    const int nt  = idx >> 12;         // 0..47
    rkB[dir * RKB_PER_DIR + idx] = f2bf(rk[(kc * 8 + i) * H3 + nt * 16 + col]);
}

// ---------------------------------------------------------------- pack W
// Wp[nt][kc][col][i] = bf16( W[kc*8+i][nt*16+col] ), zero-padded cols.
__global__ __launch_bounds__(256) void pack_W_kernel(
    const float* __restrict__ W, unsigned short* __restrict__ Wp)
{
    const int idx = blockIdx.x * 256 + threadIdx.x;   // < 416*8192
    const int i   = idx & 7;
    const int col = (idx >> 3) & 15;
    const int kc  = (idx >> 7) & 63;
    const int nt  = idx >> 13;
    const int k = kc * 8 + i;
    const int c = nt * 16 + col;
    const float v = (c < C) ? W[k * C + c] : 0.f;
    Wp[idx] = f2bf(v);
}

// ---------------------------------------------------------------- pack xb
// xb[t*32+b][k] = bf16( x[b][t][k] ) -- time-major, coalesced in k.
__global__ __launch_bounds__(256) void pack_xb_kernel(
    const float* __restrict__ x, unsigned short* __restrict__ xb)
{
    const int idx = blockIdx.x * 256 + threadIdx.x;   // < 2,621,440
    const int k   = idx & 511;
    const int row = idx >> 9;          // t*32+b
    const int t   = row >> 5;
    const int b   = row & 31;
    xb[idx] = f2bf(x[(b * T + t) * 512 + k]);
}

// ---------------------------------------------------------------- pack kern
// kernP[dir][nt48][kc64][col16][i8] = bf16( kern[kc*8+i][nt*16+col] )
__global__ __launch_bounds__(256) void pack_kern_kernel(
    const float* __restrict__ kf, const float* __restrict__ kb,
    unsigned short* __restrict__ kernP)
{
    const int idx = blockIdx.x * 256 + threadIdx.x;   // < 393216
    const int dir = blockIdx.y;
    const float* kern = dir ? kb : kf;
    const int i   = idx & 7;
    const int col = (idx >> 3) & 15;
    const int kc  = (idx >> 7) & 63;
    const int nt  = idx >> 13;         // 0..47
    kernP[dir * KP_PER_DIR + idx] = f2bf(kern[(kc * 8 + i) * H3 + nt * 16 + col]);
}

// ---------------------------------------------------------------- K1: proj (MFMA)
// grid (240, 2). Output xpb in BF16 (scan reads it).
__global__ __launch_bounds__(256) void proj_mfma_kernel(
    const unsigned short* __restrict__ xb,     // [5120][512] bf16
    const unsigned short* __restrict__ kernP,  // [2][48][64][16][8]
    const float* __restrict__ bias_f,          // [2][H3]
    const float* __restrict__ bias_b,
    unsigned short* __restrict__ xpb)          // [2*5120][768] bf16
{
    const int bid = blockIdx.x;
    const int ct  = bid / 40;          // 0..5
    const int rt  = bid % 40;          // 0..39
    const int dir = blockIdx.y;
    const int lane = threadIdx.x & 63;
    const int wid  = threadIdx.x >> 6;
    const int wm = wid >> 1, wn = wid & 1;
    const int rowBase = rt * 128 + wm * 64;
    const int lrow = lane & 15;
    const int lk8  = lane >> 4;        // 0..3
    const float* bias = dir ? bias_b : bias_f;

    float4v acc[4][4];
#pragma unroll
    for (int i = 0; i < 4; ++i)
#pragma unroll
        for (int k = 0; k < 4; ++k) acc[i][k] = (float4v){0.f, 0.f, 0.f, 0.f};

    const short* A  = (const short*)xb;
    const short* Bp = (const short*)(kernP + dir * KP_PER_DIR);
    const int ntBase = ct * 8 + wn * 4;

    int arow[4];
#pragma unroll
    for (int mt = 0; mt < 4; ++mt) {
        const int r0 = rowBase + mt * 16;
        const int s  = r0 >> 5;
        arow[mt] = (dir ? (159 - s) : s) * 32 + (r0 & 31);
    }

    for (int k0 = 0; k0 < 512; k0 += 32) {
        short8v aF[4], bF[4];
#pragma unroll
        for (int mt = 0; mt < 4; ++mt)
            aF[mt] = *(const short8v*)&A[(arow[mt] + lrow) * 512 + k0 + lk8 * 8];
#pragma unroll
        for (int ntw = 0; ntw < 4; ++ntw)
            bF[ntw] = *(const short8v*)&Bp[((ntBase + ntw) * 64 + (k0 >> 3) + lk8) * 128 + lrow * 8];
#pragma unroll
        for (int mt = 0; mt < 4; ++mt)
#pragma unroll
            for (int ntw = 0; ntw < 4; ++ntw)
                acc[mt][ntw] = __builtin_amdgcn_mfma_f32_16x16x32_bf16(
                    aF[mt], bF[ntw], acc[mt][ntw], 0, 0, 0);
    }

    const int orow = (lane >> 4) * 4;   // C/D: col=lane&15, row=(lane>>4)*4+reg
#pragma unroll
    for (int ntw = 0; ntw < 4; ++ntw) {
        const int c = (ntBase + ntw) * 16 + lrow;   // 0..767
        const float bc = bias[c];
#pragma unroll
        for (int mt = 0; mt < 4; ++mt)
#pragma unroll
            for (int v = 0; v < 4; ++v)
                xpb[(size_t)(dir * 5120 + rowBase + mt * 16 + orow + v) * H3 + c]
                    = f2bf(acc[mt][ntw][v] + bc);
    }
}

// ---------------------------------------------------------------- K2: scan v6 (MFMA) -- R9 proven
// grid 64 = (dir<<5)|b, block 768 = 12 waves. Wave w owns gate cols
// [w*64, +64) = 4 n-tiles; B-frags (128 regs) loaded once.
// Per step: A = h row-replicated; result read from row 0.
__global__ __launch_bounds__(768, 3) void gru_scan_v6(
    const unsigned short* __restrict__ xpb, // [2][T][B][H3] bf16
    const unsigned short* __restrict__ rkB, // [2][48][32][16][8]
    const float* __restrict__ bias_f,
    const float* __restrict__ bias_b,
    __hip_bfloat16* __restrict__ hcatb)    // [T][B][2H] bf16
{
    const int bid = blockIdx.x;
    const int dir = bid >> 5;
    const int b   = bid & 31;
    const int tid = threadIdx.x;
    const int wv  = tid >> 6;          // 0..11
    const int lane = tid & 63;
    const int lrow = lane & 15;
    const int lk8  = lane >> 4;        // 0..3
    const int j   = tid & 255;
    const float* bias = dir ? bias_b : bias_f;
    const short* Bp = (const short*)(rkB + (size_t)dir * RKB_PER_DIR);

    short8v bw[32];                    // [nt 0..3][kk 0..7]
#pragma unroll
    for (int i = 0; i < 4; ++i)
#pragma unroll
        for (int kk = 0; kk < 8; ++kk)
            bw[i * 8 + kk] = *(const short8v*)
                &Bp[(((wv * 4 + i) * 32) + kk * 4 + lk8) * 128 + lrow * 8];

    float rbz = 0.f, rbr = 0.f, rbh = 0.f;
    if (tid < 256) {
        rbz = bias[H3 + j];
        rbr = bias[H3 + 256 + j];
        rbh = bias[H3 + 512 + j];
    }

    __shared__ float hfp[256];                         // fp32 h (for z*h_old)
    __shared__ __align__(16) unsigned short hus[256];  // bf16 h (A operand)
    __shared__ float sums[768];                        // gate dots
    if (tid < 256) { hfp[tid] = 0.f; hus[tid] = 0; }
    __syncthreads();

    for (int s = 0; s < T; ++s) {
        float xz = 0.f, xr = 0.f, xh = 0.f;
        if (tid < 256) {               // issue early; hides under MFMA phase
            const unsigned short* xrow = xpb + ((size_t)(dir * T + s) * B + b) * H3;
            xz = bf2f(xrow[j]);
            xr = bf2f(xrow[256 + j]);
            xh = bf2f(xrow[512 + j]);
        }

        float4v a0 = {0.f,0.f,0.f,0.f}, a1 = {0.f,0.f,0.f,0.f};
        float4v a2 = {0.f,0.f,0.f,0.f}, a3 = {0.f,0.f,0.f,0.f};
#pragma unroll
        for (int kk = 0; kk < 8; ++kk) {
            short8v aF = *(const short8v*)&hus[kk * 32 + lk8 * 8];  // broadcast
            a0 = __builtin_amdgcn_mfma_f32_16x16x32_bf16(aF, bw[0 * 8 + kk], a0, 0, 0, 0);
            a1 = __builtin_amdgcn_mfma_f32_16x16x32_bf16(aF, bw[1 * 8 + kk], a1, 0, 0, 0);
            a2 = __builtin_amdgcn_mfma_f32_16x16x32_bf16(aF, bw[2 * 8 + kk], a2, 0, 0, 0);
            a3 = __builtin_amdgcn_mfma_f32_16x16x32_bf16(aF, bw[3 * 8 + kk], a3, 0, 0, 0);
        }
        if (lane < 16) {               // row 0 = lanes 0..15, reg 0
            sums[(wv * 4 + 0) * 16 + lane] = a0[0];
            sums[(wv * 4 + 1) * 16 + lane] = a1[0];
            sums[(wv * 4 + 2) * 16 + lane] = a2[0];
            sums[(wv * 4 + 3) * 16 + lane] = a3[0];
        }
        __syncthreads();               // sums visible

        if (tid < 256) {
            const float sz = sums[j];
            const float sr = sums[256 + j];
            const float sh = sums[512 + j];
            const float z  = 1.f / (1.f + __expf(-(xz + sz + rbz)));
            const float r  = 1.f / (1.f + __expf(-(xr + sr + rbr)));
            const float pre = xh + r * (sh + rbh);
            const float e2  = __expf(2.f * pre);
            const float hh  = 1.f - 2.f / (e2 + 1.f);   // tanh, inf-safe
            const float hn  = z * hfp[j] + (1.f - z) * hh;
            hfp[j] = hn;
            hus[j] = f2bf(hn);
            const int ta = dir ? (T - 1 - s) : s;
            hcatb[(ta * B + b) * 512 + dir * 256 + j] = __float2bfloat16(hn);
        }
        __syncthreads();               // h_{s+1} ready
    }
}

// ---------------------------------------------------------------- K3: cls v3 (MFMA, 64-row LDS A)
// grid 2080 = 26 ctn x 80 rt, ct-major. Block 64 rows x 256 cols, 4 waves
// 2x2 -> wave 32x128 (mt=2, nt=8). As = 64 KB -> 2 blocks/CU (vs 1 at 128KB)
// so the stage's global-load latency overlaps the other block's MFMA phase.
// XOR swizzle byte ^= (row&7)<<4 (1024-B row stride = 16-way conflict else).
__global__ __launch_bounds__(256) void cls_mfma3_kernel(
    const unsigned short* __restrict__ hcatb,  // [5120][512] bf16
    const unsigned short* __restrict__ Wp,     // [416][64][16][8]
    const float* __restrict__ bias,
    float* __restrict__ out)
{
    const int bid = blockIdx.x;
    const int ctn = bid / 80;          // 0..25
    const int rt  = bid % 80;          // 0..79
    const int tid = threadIdx.x;
    const int lane = tid & 63;
    const int wid  = tid >> 6;
    const int wm = wid >> 1, wn = wid & 1;
    const int lrow = lane & 15;
    const int lk8  = lane >> 4;        // 0..3
    const int r0   = rt * 64;

    __shared__ __align__(16) unsigned short As[64 * 512];   // 64 KB swizzled

    {   // stage 64x512 bf16: 16 x 16B chunks per thread, coalesced global
        const uint4* src = (const uint4*)hcatb;    // row = 64 uint4
        for (int it = 0; it < 16; ++it) {
            const int v   = it * 256 + tid;        // 0..4095
            const int row = v >> 6;
            const int c16 = (v & 63) << 4;         // byte offset in row
            const uint4 d = src[(size_t)(r0 + row) * 64 + (v & 63)];
            *(uint4*)((char*)As + row * 1024 + (c16 ^ ((row & 7) << 4))) = d;
        }
    }
    __syncthreads();

    float4v acc[2][8];
#pragma unroll
    for (int i = 0; i < 2; ++i)
#pragma unroll
        for (int k = 0; k < 8; ++k) acc[i][k] = (float4v){0.f, 0.f, 0.f, 0.f};

    const short* Bp = (const short*)Wp;
    const int ntBase = ctn * 16 + wn * 8;

    for (int k0 = 0; k0 < 512; k0 += 32) {
        short8v aF[2], bF[8];
#pragma unroll
        for (int mt = 0; mt < 2; ++mt) {
            const int row = wm * 32 + mt * 16 + lrow;
            const int cb  = (k0 * 2 + lk8 * 16) ^ ((row & 7) << 4);
            aF[mt] = *(const short8v*)((const char*)As + row * 1024 + cb);
        }
#pragma unroll
        for (int ntw = 0; ntw < 8; ++ntw)
            bF[ntw] = *(const short8v*)&Bp[((ntBase + ntw) * 64 + (k0 >> 3) + lk8) * 128 + lrow * 8];
#pragma unroll
        for (int mt = 0; mt < 2; ++mt)
#pragma unroll
            for (int ntw = 0; ntw < 8; ++ntw)
                acc[mt][ntw] = __builtin_amdgcn_mfma_f32_16x16x32_bf16(
                    aF[mt], bF[ntw], acc[mt][ntw], 0, 0, 0);
    }

    const int orow = (lane >> 4) * 4;   // C/D: col=lane&15, row=(lane>>4)*4+reg
#pragma unroll
    for (int ntw = 0; ntw < 8; ++ntw) {
        const int c = (ntBase + ntw) * 16 + lrow;
        if (c >= C) continue;
        const float bc = bias[c];
#pragma unroll
        for (int mt = 0; mt < 2; ++mt)
#pragma unroll
            for (int v = 0; v < 4; ++v)
                out[(size_t)(r0 + wm * 32 + mt * 16 + orow + v) * C + c]
                    = acc[mt][ntw][v] + bc;
    }
}

// ============================ fallback fp32 path (small ws) ============================
__global__ __launch_bounds__(256) void proj_kernel(
    const float* __restrict__ x, const float* __restrict__ kf,
    const float* __restrict__ kb, const float* __restrict__ bias_f,
    const float* __restrict__ bias_b, float* __restrict__ xp)
{
    const int ct  = blockIdx.x;
    const int s   = blockIdx.y;
    const int dir = blockIdx.z;
    const int tid = threadIdx.x;
    const int t   = dir ? (T - 1 - s) : s;
    const float* kern = dir ? kb : kf;
    const float* bias = dir ? bias_b : bias_f;

    __shared__ float xs[32 * 512];
    for (int it = 0; it < 16; ++it) {
        int v = it * 256 + tid, row = v >> 7, k4 = v & 127;
        *(float4*)&xs[(row << 9) + (k4 << 2)] =
            *(const float4*)&x[((row * T + t) << 9) + (k4 << 2)];
    }
    __syncthreads();

    const int col = ct * 256 + tid;
    float acc[32];
#pragma unroll
    for (int r = 0; r < 32; ++r) acc[r] = 0.f;
    for (int k = 0; k < 512; k += 4) {
        float w0 = kern[(k + 0) * H3 + col];
        float w1 = kern[(k + 1) * H3 + col];
        float w2 = kern[(k + 2) * H3 + col];
        float w3 = kern[(k + 3) * H3 + col];
#pragma unroll
        for (int r = 0; r < 32; ++r) {
            float4 xv = *(const float4*)&xs[(r << 9) + k];
            acc[r] += xv.x * w0 + xv.y * w1 + xv.z * w2 + xv.w * w3;
        }
    }
    const float bb = bias[col];
    for (int r = 0; r < 32; ++r)
        xp[((dir * T + s) * B + r) * H3 + col] = acc[r] + bb;
}

__global__ __launch_bounds__(1024) void gru_scan_f32(
    const float* __restrict__ xp,
    const float* __restrict__ rk_f, const float* __restrict__ rk_b,
    const float* __restrict__ bias_f, const float* __restrict__ bias_b,
    float* __restrict__ hcat)
{
    const int bid = blockIdx.x;
    const int dir = bid >> 5;
    const int b   = bid & 31;
    const int tid = threadIdx.x;
    const int kg  = tid >> 8;
    const int j   = tid & 255;
    const int k0  = kg << 6;
    const float* rk   = dir ? rk_b : rk_f;
    const float* bias = dir ? bias_b : bias_f;
    const float rbz = bias[H3 + j];
    const float rbr = bias[H3 + 256 + j];
    const float rbh = bias[H3 + 512 + j];

    __shared__ float h[256];
    __shared__ float part[3][4][256];
    if (tid < 256) h[tid] = 0.f;
    __syncthreads();

    for (int s = 0; s < T; ++s) {
        const float* xrow = xp + ((dir * T + s) * B + b) * H3;
        float az = 0.f, ar = 0.f, ah = 0.f;
#pragma unroll 4
        for (int k = k0; k < k0 + 64; k += 4) {
            float4 h4 = *(const float4*)&h[k];
            const float* rkp = rk + k * H3 + j;
            az += h4.x * rkp[0];       ar += h4.x * rkp[256];       ah += h4.x * rkp[512];
            az += h4.y * rkp[H3];      ar += h4.y * rkp[H3+256];    ah += h4.y * rkp[H3+512];
            az += h4.z * rkp[2*H3];    ar += h4.z * rkp[2*H3+256];  ah += h4.z * rkp[2*H3+512];
            az += h4.w * rkp[3*H3];    ar += h4.w * rkp[3*H3+256];  ah += h4.w * rkp[3*H3+512];
        }
        part[0][kg][j] = az; part[1][kg][j] = ar; part[2][kg][j] = ah;
        __syncthreads();
        if (tid < 256) {
            const float sz = part[0][0][tid]+part[0][1][tid]+part[0][2][tid]+part[0][3][tid];
            const float sr = part[1][0][tid]+part[1][1][tid]+part[1][2][tid]+part[1][3][tid];
            const float sh = part[2][0][tid]+part[2][1][tid]+part[2][2][tid]+part[2][3][tid];
            const float xz = xrow[tid], xr = xrow[256+tid], xh = xrow[512+tid];
            const float z  = 1.f / (1.f + __expf(-(xz + sz + rbz)));
            const float r  = 1.f / (1.f + __expf(-(xr + sr + rbr)));
            const float pre = xh + r * (sh + rbh);
            const float e2  = __expf(2.f * pre);
            const float hh  = 1.f - 2.f / (e2 + 1.f);
            const float hn  = z * h[tid] + (1.f - z) * hh;
            h[tid] = hn;
            const int ta = dir ? (T - 1 - s) : s;
            hcat[(ta * B + b) * (2 * H) + dir * H + tid] = hn;
        }
        __syncthreads();
    }
}

__global__ __launch_bounds__(256) void cls_f32_kernel(
    const float* __restrict__ hcat, const float* __restrict__ W,
    const float* __restrict__ bias, float* __restrict__ out)
{
    const int bid = blockIdx.x;
    const int ct  = bid / 160;
    const int rt  = bid % 160;
    const int tid = threadIdx.x;
    const int r0  = rt * 32;

    __shared__ float hs[32 * 512];
    for (int it = 0; it < 16; ++it) {
        int v = it * 256 + tid, row = v >> 7, k4 = v & 127;
        *(float4*)&hs[(row << 9) + (k4 << 2)] =
            *(const float4*)&hcat[((r0 + row) << 9) + (k4 << 2)];
    }
    __syncthreads();

    const int c0 = ct * 512 + tid;
    const int c1 = c0 + 256;
    const bool v1 = (c1 < C);
    float acc0[32], acc1[32];
#pragma unroll
    for (int r = 0; r < 32; ++r) { acc0[r] = 0.f; acc1[r] = 0.f; }
    for (int k = 0; k < 512; k += 4) {
        const float* wp = W + k * C;
        float w00 = wp[c0], w01 = wp[C+c0], w02 = wp[2*C+c0], w03 = wp[3*C+c0];
        float w10 = v1 ? wp[c1] : 0.f, w11 = v1 ? wp[C+c1] : 0.f;
        float w12 = v1 ? wp[2*C+c1] : 0.f, w13 = v1 ? wp[3*C+c1] : 0.f;
#pragma unroll
        for (int r = 0; r < 32; ++r) {
            float4 hv = *(const float4*)&hs[(r << 9) + k];
            acc0[r] += hv.x*w00 + hv.y*w01 + hv.z*w02 + hv.w*w03;
            acc1[r] += hv.x*w10 + hv.y*w11 + hv.z*w12 + hv.w*w13;
        }
    }
    const float b0 = bias[c0];
    const float b1 = v1 ? bias[c1] : 0.f;
    for (int r = 0; r < 32; ++r) {
        out[(size_t)(r0+r)*C + c0] = acc0[r] + b0;
        if (v1) out[(size_t)(r0+r)*C + c1] = acc1[r] + b1;
    }
}

// ---------------------------------------------------------------- launch
extern "C" void kernel_launch(void* const* d_in, const int* in_sizes, int n_in,
                              void* d_out, int out_size, void* d_ws, size_t ws_size,
                              hipStream_t stream) {
    const float* x     = (const float*)d_in[0];
    const float* kf    = (const float*)d_in[1];
    const float* rkf   = (const float*)d_in[2];
    const float* biasf = (const float*)d_in[3];
    const float* kb    = (const float*)d_in[4];
    const float* rkb   = (const float*)d_in[5];
    const float* biasb = (const float*)d_in[6];
    const float* W     = (const float*)d_in[7];
    const float* bvec  = (const float*)d_in[8];
    float* out = (float*)d_out;

    const size_t rkB_bytes   = (size_t)2 * RKB_PER_DIR * 2;       //   786,432
    const size_t Wp_bytes    = (size_t)NT16 * 8192 * 2;           // 6,815,744
    const size_t hcatb_bytes = (size_t)T * B * 2 * H * 2;         // 5,242,880
    const size_t planA_bytes = rkB_bytes + Wp_bytes + hcatb_bytes;

    // d_out (135.7 MB) carved up; all regions dead before cls writes out:
    //   [0, 15.7 MB)        xpb   [2*5120][768] bf16
    //   [31.5, 36.7 MB)     xb    [5120][512] bf16
    //   [36.7, 38.3 MB)     kernP [2][393216] bf16
    unsigned short* xpb   = (unsigned short*)out;
    unsigned short* xb    = (unsigned short*)((char*)out + (size_t)2 * 5120 * H3 * 4);
    unsigned short* kernP = (unsigned short*)((char*)xb + (size_t)5120 * 512 * 2);

    if (ws_size >= planA_bytes) {
        char* wsb = (char*)d_ws;
        unsigned short* rkB   = (unsigned short*)wsb;
        unsigned short* Wp    = (unsigned short*)(wsb + rkB_bytes);
        __hip_bfloat16* hcatb = (__hip_bfloat16*)(wsb + rkB_bytes + Wp_bytes);

        pack_rkB_kernel<<<dim3(768, 2), 256, 0, stream>>>(rkf, rkb, rkB);
        pack_W_kernel<<<13312, 256, 0, stream>>>(W, Wp);
        pack_xb_kernel<<<10240, 256, 0, stream>>>(x, xb);
        pack_kern_kernel<<<dim3(1536, 2), 256, 0, stream>>>(kf, kb, kernP);

        proj_mfma_kernel<<<dim3(240, 2), 256, 0, stream>>>(xb, kernP, biasf, biasb, xpb);

        gru_scan_v6<<<64, 768, 0, stream>>>(xpb, rkB, biasf, biasb, hcatb);

        cls_mfma3_kernel<<<2080, 256, 0, stream>>>((const unsigned short*)hcatb,
                                                   Wp, bvec, out);
    } else {
        // fp32 fallback (round-2 path)
        float* xp   = out;
        float* hcat = (float*)d_ws;     // 10.5 MB
        dim3 g1(3, T, 2);
        proj_kernel<<<g1, 256, 0, stream>>>(x, kf, kb, biasf, biasb, xp);
        gru_scan_f32<<<64, 1024, 0, stream>>>(xp, rkf, rkb, biasf, biasb, hcat);
        cls_f32_kernel<<<13 * 160, 256, 0, stream>>>(hcat, W, bvec, out);
    }
}